// Round 1
// baseline (5800.723 us; speedup 1.0000x reference)
//
#include <hip/hip_runtime.h>
#include <math.h>

// Model8: 3-layer GATv2 (G=10) over N=100K nodes / 3.3M edges (incl self-loops),
// + policy head (M=4096 moves x 48 orders) + attention-pooled value head.
// R1 strategy: atomic-based edge softmax (no segment_max needed: |e| <~ 1.5),
// node-parallel small matvecs with weights in LDS, wave-per-move policy.
// ws usage: ~34 MB fp32.

#define PAD 12  // padded row stride for [N,10] arrays -> 48B rows, float4-able

__device__ __forceinline__ float lrelu02(float v) { return v > 0.f ? v : 0.2f * v; }

// x_ = relu(x1 @ init_W + init_b); also zero the value-head accumulator.
__global__ void k_init(const float* __restrict__ x1, const float* __restrict__ W,
                       const float* __restrict__ b, float* __restrict__ xo,
                       float* __restrict__ vsums, int N)
{
    __shared__ float sW[150];
    __shared__ float sb[10];
    int t = threadIdx.x;
    if (t < 150) sW[t] = W[t];
    if (t < 10) sb[t] = b[t];
    if (blockIdx.x == 0 && t < 16) vsums[t] = 0.f;
    __syncthreads();
    int n = blockIdx.x * blockDim.x + t;
    if (n >= N) return;
    float f[15];
#pragma unroll
    for (int k = 0; k < 15; ++k) f[k] = x1[n * 15 + k];
#pragma unroll
    for (int g = 0; g < 10; ++g) {
        float s = sb[g];
#pragma unroll
        for (int k = 0; k < 15; ++k) s += f[k] * sW[k * 10 + g];
        xo[n * PAD + g] = fmaxf(s, 0.f);
    }
    xo[n * PAD + 10] = 0.f;
    xo[n * PAD + 11] = 0.f;
}

// Per-node: xl = f @ Wl, xr = f @ Wr where f = concat(s0,s1,s2,x1) (NS of s* used).
// Also zero this layer's accumulator rows (acc[.,10] doubles as denom).
template <int NS>
__global__ void k_transform(const float* __restrict__ s0, const float* __restrict__ s1,
                            const float* __restrict__ s2, const float* __restrict__ x1,
                            const float* __restrict__ Wl, const float* __restrict__ Wr,
                            float* __restrict__ XL, float* __restrict__ XR,
                            float* __restrict__ acc, int N)
{
    constexpr int FIN = NS * 10 + 15;
    __shared__ float sWl[FIN * 10];
    __shared__ float sWr[FIN * 10];
    for (int i = threadIdx.x; i < FIN * 10; i += blockDim.x) {
        sWl[i] = Wl[i];
        sWr[i] = Wr[i];
    }
    __syncthreads();
    int n = blockIdx.x * blockDim.x + threadIdx.x;
    if (n >= N) return;
    float f[FIN];
    int o = 0;
    if constexpr (NS >= 1) {
#pragma unroll
        for (int g = 0; g < 10; ++g) f[o++] = s0[n * PAD + g];
    }
    if constexpr (NS >= 2) {
#pragma unroll
        for (int g = 0; g < 10; ++g) f[o++] = s1[n * PAD + g];
    }
    if constexpr (NS >= 3) {
#pragma unroll
        for (int g = 0; g < 10; ++g) f[o++] = s2[n * PAD + g];
    }
#pragma unroll
    for (int k = 0; k < 15; ++k) f[o++] = x1[n * 15 + k];
#pragma unroll
    for (int g = 0; g < 10; ++g) {
        float al = 0.f, ar = 0.f;
#pragma unroll
        for (int k = 0; k < FIN; ++k) {
            al += f[k] * sWl[k * 10 + g];
            ar += f[k] * sWr[k * 10 + g];
        }
        XL[n * PAD + g] = al;
        XR[n * PAD + g] = ar;
    }
    XL[n * PAD + 10] = 0.f; XL[n * PAD + 11] = 0.f;
    XR[n * PAD + 10] = 0.f; XR[n * PAD + 11] = 0.f;
#pragma unroll
    for (int g = 0; g < PAD; ++g) acc[n * PAD + g] = 0.f;
}

// Edge pass: e = lrelu(xl[s]+xr[d])@att; ex = exp(e) (no max needed, |e| small);
// acc[d][0..9] += ex*xl[s]; acc[d][10] += ex.
__global__ void k_edge(const int* __restrict__ esrc, const int* __restrict__ edst,
                       int E, int Etot,
                       const float* __restrict__ XL, const float* __restrict__ XR,
                       const float* __restrict__ att, float* __restrict__ acc)
{
    int i = blockIdx.x * blockDim.x + threadIdx.x;
    if (i >= Etot) return;
    int s, d;
    if (i < E) { s = esrc[i]; d = edst[i]; }
    else { s = i - E; d = s; }
    const float4* pl = (const float4*)(XL + s * PAD);
    const float4* pr = (const float4*)(XR + d * PAD);
    float4 l0 = pl[0], l1 = pl[1], l2 = pl[2];
    float4 r0 = pr[0], r1 = pr[1], r2 = pr[2];
    float xl[10] = {l0.x, l0.y, l0.z, l0.w, l1.x, l1.y, l1.z, l1.w, l2.x, l2.y};
    float xr[10] = {r0.x, r0.y, r0.z, r0.w, r1.x, r1.y, r1.z, r1.w, r2.x, r2.y};
    float e = 0.f;
#pragma unroll
    for (int g = 0; g < 10; ++g) e += lrelu02(xl[g] + xr[g]) * att[g];
    float ex = __expf(e);
    float* ad = acc + d * PAD;
#pragma unroll
    for (int g = 0; g < 10; ++g) atomicAdd(&ad[g], ex * xl[g]);
    atomicAdd(&ad[10], ex);
}

// out = relu(acc/denom + bias)
__global__ void k_finalize(const float* __restrict__ acc, const float* __restrict__ b,
                           float* __restrict__ xo, int N)
{
    __shared__ float sb[10];
    if (threadIdx.x < 10) sb[threadIdx.x] = b[threadIdx.x];
    __syncthreads();
    int n = blockIdx.x * blockDim.x + threadIdx.x;
    if (n >= N) return;
    float inv = 1.f / acc[n * PAD + 10];
#pragma unroll
    for (int g = 0; g < 10; ++g)
        xo[n * PAD + g] = fmaxf(acc[n * PAD + g] * inv + sb[g], 0.f);
    xo[n * PAD + 10] = 0.f;
    xo[n * PAD + 11] = 0.f;
}

// Value head accumulation: per node w = exp(v@va+vab), wv = w*(v@vv+vvb).
// Block-reduce 11 components, one atomicAdd set per block. No max (|s| <~ 1.5).
__global__ void k_value(const float* __restrict__ xc, const float* __restrict__ x1,
                        const float* __restrict__ x2,
                        const float* __restrict__ vtW, const float* __restrict__ vtb,
                        const float* __restrict__ vaW, const float* __restrict__ vab,
                        const float* __restrict__ vvW, const float* __restrict__ vvb,
                        float* __restrict__ vsums, int N)
{
    __shared__ float sW[580];   // 29x20
    __shared__ float svv[200];  // 20x10
    __shared__ float sb20[20], sva[20], svvb[10], sx2[4];
    __shared__ float svab;
    __shared__ float sred[4][11];
    int t = threadIdx.x;
    for (int i = t; i < 580; i += blockDim.x) sW[i] = vtW[i];
    for (int i = t; i < 200; i += blockDim.x) svv[i] = vvW[i];
    if (t < 20) sb20[t] = vtb[t];
    if (t >= 32 && t < 52) sva[t - 32] = vaW[t - 32];
    if (t >= 64 && t < 74) svvb[t - 64] = vvb[t - 64];
    if (t >= 96 && t < 100) sx2[t - 96] = x2[t - 96];
    if (t == 128) svab = vab[0];
    __syncthreads();
    int n = blockIdx.x * blockDim.x + t;
    float w = 0.f;
    float wv[10];
#pragma unroll
    for (int c = 0; c < 10; ++c) wv[c] = 0.f;
    if (n < N) {
        float f[29];
#pragma unroll
        for (int k = 0; k < 10; ++k) f[k] = xc[n * PAD + k];
#pragma unroll
        for (int k = 0; k < 15; ++k) f[10 + k] = x1[n * 15 + k];
#pragma unroll
        for (int k = 0; k < 4; ++k) f[25 + k] = sx2[k];
        float v[20];
#pragma unroll
        for (int j = 0; j < 20; ++j) {
            float s = sb20[j];
#pragma unroll
            for (int k = 0; k < 29; ++k) s += f[k] * sW[k * 20 + j];
            v[j] = fmaxf(s, 0.f);
        }
        float sc = svab;
#pragma unroll
        for (int j = 0; j < 20; ++j) sc += v[j] * sva[j];
        w = __expf(sc);
#pragma unroll
        for (int c = 0; c < 10; ++c) {
            float t2 = svvb[c];
#pragma unroll
            for (int j = 0; j < 20; ++j) t2 += v[j] * svv[j * 10 + c];
            wv[c] = w * t2;
        }
    }
#pragma unroll
    for (int off = 32; off > 0; off >>= 1) {
        w += __shfl_xor(w, off);
#pragma unroll
        for (int c = 0; c < 10; ++c) wv[c] += __shfl_xor(wv[c], off);
    }
    int wave = t >> 6, lane = t & 63;
    if (lane == 0) {
        sred[wave][0] = w;
#pragma unroll
        for (int c = 0; c < 10; ++c) sred[wave][1 + c] = wv[c];
    }
    __syncthreads();
    if (t == 0) {
#pragma unroll
        for (int c = 0; c < 11; ++c) {
            float s = sred[0][c] + sred[1][c] + sred[2][c] + sred[3][c];
            atomicAdd(&vsums[c], s);
        }
    }
}

// V = tanh(relu(wv/w) @ vl_W + vl_b)
__global__ void k_value2(const float* __restrict__ vsums, const float* __restrict__ vlW,
                         const float* __restrict__ vlb, float* __restrict__ out)
{
    if (threadIdx.x == 0 && blockIdx.x == 0) {
        float inv = 1.f / vsums[0];
        float V = vlb[0];
#pragma unroll
        for (int j = 0; j < 10; ++j) V += fmaxf(vsums[1 + j] * inv, 0.f) * vlW[j];
        out[0] = tanhf(V);
    }
}

// Policy: one wave per move; lane<32 -> attack order, lane in [32,48) -> deploy order.
__global__ __launch_bounds__(256) void k_policy(
    const int* __restrict__ asrc, const int* __restrict__ adst,
    const float* __restrict__ aarm,
    const int* __restrict__ dtgt, const float* __restrict__ darm,
    const float* __restrict__ xc, const float* __restrict__ x1,
    const float* __restrict__ atW, const float* __restrict__ atb,
    const float* __restrict__ dtW, const float* __restrict__ dtb,
    const float* __restrict__ oaW, const float* __restrict__ oab,
    const float* __restrict__ ovW, const float* __restrict__ ovb,
    float* __restrict__ pm, int M)
{
    __shared__ float sat[960];  // 48x20
    __shared__ float sdt[460];  // 23x20
    __shared__ float satb[20], sdtb[20], soa[20], sov[20];
    __shared__ float soab, sovb;
    for (int i = threadIdx.x; i < 960; i += 256) sat[i] = atW[i];
    for (int i = threadIdx.x; i < 460; i += 256) sdt[i] = dtW[i];
    if (threadIdx.x < 20) {
        satb[threadIdx.x] = atb[threadIdx.x];
        sdtb[threadIdx.x] = dtb[threadIdx.x];
        soa[threadIdx.x] = oaW[threadIdx.x];
        sov[threadIdx.x] = ovW[threadIdx.x];
    }
    if (threadIdx.x == 32) { soab = oab[0]; sovb = ovb[0]; }
    __syncthreads();
    int wave = threadIdx.x >> 6, lane = threadIdx.x & 63;
    int m = blockIdx.x * 4 + wave;
    float asc = -1e30f, vsc = 0.f;
    if (m < M) {
        float ord[20];
        bool have = false;
        if (lane < 32) {
            int a = lane;
            int s = asrc[m * 32 + a], d = adst[m * 32 + a];
            float arm = aarm[m * 32 + a];
            float feat[48];
#pragma unroll
            for (int g = 0; g < 10; ++g) feat[g] = xc[s * PAD + g];
#pragma unroll
            for (int g = 0; g < 10; ++g) feat[10 + g] = xc[d * PAD + g];
#pragma unroll
            for (int k = 0; k < 12; ++k) feat[20 + k] = x1[s * 15 + 3 + k];
            float x1d[15];
#pragma unroll
            for (int k = 0; k < 15; ++k) x1d[k] = x1[d * 15 + k];
#pragma unroll
            for (int k = 0; k < 14; ++k) feat[32 + k] = x1d[1 + k];
            feat[46] = arm;
            feat[47] = 0.6f * arm - 0.7f * (x1d[3] + x1d[4]);
#pragma unroll
            for (int j = 0; j < 20; ++j) {
                float s2 = satb[j];
#pragma unroll
                for (int k = 0; k < 48; ++k) s2 += feat[k] * sat[k * 20 + j];
                ord[j] = fmaxf(s2, 0.f);
            }
            have = true;
        } else if (lane < 48) {
            int dd = lane - 32;
            int tg = dtgt[m * 16 + dd];
            float arm = darm[m * 16 + dd];
            float feat[23];
#pragma unroll
            for (int g = 0; g < 10; ++g) feat[g] = xc[tg * PAD + g];
#pragma unroll
            for (int k = 0; k < 12; ++k) feat[10 + k] = x1[tg * 15 + 3 + k];
            feat[22] = arm;
#pragma unroll
            for (int j = 0; j < 20; ++j) {
                float s2 = sdtb[j];
#pragma unroll
                for (int k = 0; k < 23; ++k) s2 += feat[k] * sdt[k * 20 + j];
                ord[j] = fmaxf(s2, 0.f);
            }
            have = true;
        }
        if (have) {
            asc = soab; vsc = sovb;
#pragma unroll
            for (int j = 0; j < 20; ++j) {
                asc += ord[j] * soa[j];
                vsc += ord[j] * sov[j];
            }
        }
    }
    float mx = asc;
#pragma unroll
    for (int off = 32; off > 0; off >>= 1) mx = fmaxf(mx, __shfl_xor(mx, off));
    float p = (asc > -1e29f) ? __expf(asc - mx) : 0.f;
    float num = p * vsc;
    float Z = p;
#pragma unroll
    for (int off = 32; off > 0; off >>= 1) {
        Z += __shfl_xor(Z, off);
        num += __shfl_xor(num, off);
    }
    if (m < M && lane == 0) pm[m] = num / Z;
}

// out[1..M] = log_softmax(pm)
__global__ void k_logsoftmax(const float* __restrict__ pm, float* __restrict__ out, int M)
{
    __shared__ float red[16];
    __shared__ float sval;
    int t = threadIdx.x;
    int wave = t >> 6, lane = t & 63;
    float mx = -1e30f;
    for (int i = t; i < M; i += 1024) mx = fmaxf(mx, pm[i]);
#pragma unroll
    for (int off = 32; off > 0; off >>= 1) mx = fmaxf(mx, __shfl_xor(mx, off));
    if (lane == 0) red[wave] = mx;
    __syncthreads();
    if (t == 0) {
        float m2 = red[0];
        for (int i = 1; i < 16; ++i) m2 = fmaxf(m2, red[i]);
        sval = m2;
    }
    __syncthreads();
    float smax = sval;
    float sum = 0.f;
    for (int i = t; i < M; i += 1024) sum += __expf(pm[i] - smax);
#pragma unroll
    for (int off = 32; off > 0; off >>= 1) sum += __shfl_xor(sum, off);
    if (lane == 0) red[wave] = sum;
    __syncthreads();
    if (t == 0) {
        float s2 = 0.f;
        for (int i = 0; i < 16; ++i) s2 += red[i];
        sval = s2;
    }
    __syncthreads();
    float lse = smax + logf(sval);
    for (int i = t; i < M; i += 1024) out[1 + i] = pm[i] - lse;
}

extern "C" void kernel_launch(void* const* d_in, const int* in_sizes, int n_in,
                              void* d_out, int out_size, void* d_ws, size_t ws_size,
                              hipStream_t stream)
{
    const float* x1   = (const float*)d_in[0];
    const float* x2   = (const float*)d_in[1];
    const int*   edges = (const int*)d_in[2];
    const int*   asrc = (const int*)d_in[3];
    const int*   adst = (const int*)d_in[4];
    const float* aarm = (const float*)d_in[5];
    const int*   dtgt = (const int*)d_in[6];
    const float* darm = (const float*)d_in[7];
    const float* initW = (const float*)d_in[8];
    const float* initb = (const float*)d_in[9];
    const float* g1Wl = (const float*)d_in[10];
    const float* g1Wr = (const float*)d_in[11];
    const float* g1att = (const float*)d_in[12];
    const float* g1b = (const float*)d_in[13];
    const float* g2Wl = (const float*)d_in[14];
    const float* g2Wr = (const float*)d_in[15];
    const float* g2att = (const float*)d_in[16];
    const float* g2b = (const float*)d_in[17];
    const float* g3Wl = (const float*)d_in[18];
    const float* g3Wr = (const float*)d_in[19];
    const float* g3att = (const float*)d_in[20];
    const float* g3b = (const float*)d_in[21];
    const float* vtW = (const float*)d_in[22];
    const float* vtb = (const float*)d_in[23];
    const float* vaW = (const float*)d_in[24];
    const float* vab = (const float*)d_in[25];
    const float* vvW = (const float*)d_in[26];
    const float* vvb = (const float*)d_in[27];
    const float* vlW = (const float*)d_in[28];
    const float* vlb = (const float*)d_in[29];
    const float* atW = (const float*)d_in[30];
    const float* atb = (const float*)d_in[31];
    const float* dtW = (const float*)d_in[32];
    const float* dtb = (const float*)d_in[33];
    const float* oaW = (const float*)d_in[34];
    const float* oab = (const float*)d_in[35];
    const float* ovW = (const float*)d_in[36];
    const float* ovb = (const float*)d_in[37];

    const int N = in_sizes[0] / 15;
    const int E = in_sizes[2] / 2;
    const int M = in_sizes[3] / 32;
    const int Etot = E + N;

    float* ws = (float*)d_ws;
    size_t off = 0;
    float* XU = ws + off; off += (size_t)N * PAD;  // x_
    float* XA = ws + off; off += (size_t)N * PAD;
    float* XB = ws + off; off += (size_t)N * PAD;
    float* XC = ws + off; off += (size_t)N * PAD;
    float* XL = ws + off; off += (size_t)N * PAD;
    float* XR = ws + off; off += (size_t)N * PAD;
    float* ACC = ws + off; off += (size_t)N * PAD;  // [.,10] = denom
    float* VS = ws + off; off += 16;
    float* PM = ws + off; off += M;

    float* outp = (float*)d_out;

    const int NB = (N + 255) / 256;
    const int EB = (Etot + 255) / 256;
    const int* esrc = edges;
    const int* edst = edges + E;

    k_init<<<NB, 256, 0, stream>>>(x1, initW, initb, XU, VS, N);

    // Layer 1: f = [x_, x1]
    k_transform<1><<<NB, 256, 0, stream>>>(XU, nullptr, nullptr, x1, g1Wl, g1Wr, XL, XR, ACC, N);
    k_edge<<<EB, 256, 0, stream>>>(esrc, edst, E, Etot, XL, XR, g1att, ACC);
    k_finalize<<<NB, 256, 0, stream>>>(ACC, g1b, XA, N);

    // Layer 2: f = [xa, x_, x1]
    k_transform<2><<<NB, 256, 0, stream>>>(XA, XU, nullptr, x1, g2Wl, g2Wr, XL, XR, ACC, N);
    k_edge<<<EB, 256, 0, stream>>>(esrc, edst, E, Etot, XL, XR, g2att, ACC);
    k_finalize<<<NB, 256, 0, stream>>>(ACC, g2b, XB, N);

    // Layer 3: f = [xb, xa, x_, x1]
    k_transform<3><<<NB, 256, 0, stream>>>(XB, XA, XU, x1, g3Wl, g3Wr, XL, XR, ACC, N);
    k_edge<<<EB, 256, 0, stream>>>(esrc, edst, E, Etot, XL, XR, g3att, ACC);
    k_finalize<<<NB, 256, 0, stream>>>(ACC, g3b, XC, N);

    // Value head
    k_value<<<NB, 256, 0, stream>>>(XC, x1, x2, vtW, vtb, vaW, vab, vvW, vvb, VS, N);
    k_value2<<<1, 64, 0, stream>>>(VS, vlW, vlb, outp);

    // Policy head
    k_policy<<<(M + 3) / 4, 256, 0, stream>>>(asrc, adst, aarm, dtgt, darm, XC, x1,
                                              atW, atb, dtW, dtb, oaW, oab, ovW, ovb, PM, M);
    k_logsoftmax<<<1, 1024, 0, stream>>>(PM, outp, M);
}

// Round 2
// 599.090 us; speedup vs baseline: 9.6826x; 9.6826x over previous
//
#include <hip/hip_runtime.h>
#include <math.h>

// Model8 R2: replace atomic edge-softmax (11 fp32 atomics/edge, measured
// 19.8 G atomics/s ceiling -> 3x1836us) with a dst-sorted CSR built once per
// call (1 returning int atomic/edge) + atomic-free 8-lanes-per-node gather.

#define PAD 12  // padded row stride for [N,10] arrays -> 48B rows, float4-able

__device__ __forceinline__ float lrelu02(float v) { return v > 0.f ? v : 0.2f * v; }

// x_ = relu(x1 @ init_W + init_b); zero deg[] and value-head accumulator.
__global__ void k_init(const float* __restrict__ x1, const float* __restrict__ W,
                       const float* __restrict__ b, float* __restrict__ xo,
                       int* __restrict__ deg, float* __restrict__ vsums, int N)
{
    __shared__ float sW[150];
    __shared__ float sb[10];
    int t = threadIdx.x;
    if (t < 150) sW[t] = W[t];
    if (t < 10) sb[t] = b[t];
    if (blockIdx.x == 0 && t < 16) vsums[t] = 0.f;
    __syncthreads();
    int n = blockIdx.x * blockDim.x + t;
    if (n >= N) return;
    deg[n] = 0;
    float f[15];
#pragma unroll
    for (int k = 0; k < 15; ++k) f[k] = x1[n * 15 + k];
#pragma unroll
    for (int g = 0; g < 10; ++g) {
        float s = sb[g];
#pragma unroll
        for (int k = 0; k < 15; ++k) s += f[k] * sW[k * 10 + g];
        xo[n * PAD + g] = fmaxf(s, 0.f);
    }
    xo[n * PAD + 10] = 0.f;
    xo[n * PAD + 11] = 0.f;
}

// CSR build pass 1: degree histogram; returning atomic gives within-row slot.
__global__ void k_hist(const int* __restrict__ esrc, const int* __restrict__ edst,
                       int E, int Etot, int* __restrict__ deg, int* __restrict__ pos)
{
    int i = blockIdx.x * blockDim.x + threadIdx.x;
    if (i >= Etot) return;
    int d = (i < E) ? edst[i] : (i - E);
    pos[i] = atomicAdd(&deg[d], 1);
}

// Exclusive scan of deg -> rowptr. Two-level: per-block scan + block sums.
__global__ __launch_bounds__(1024) void k_scan1(const int* __restrict__ deg,
                                                int* __restrict__ rowptr,
                                                int* __restrict__ bsum, int N)
{
    __shared__ int wsum[16];
    int t = threadIdx.x;
    int i = blockIdx.x * 1024 + t;
    int lane = t & 63, w = t >> 6;
    int x = (i < N) ? deg[i] : 0;
    int incl = x;
#pragma unroll
    for (int off = 1; off < 64; off <<= 1) {
        int u = __shfl_up(incl, off);
        if (lane >= off) incl += u;
    }
    if (lane == 63) wsum[w] = incl;
    __syncthreads();
    int woff = 0;
    for (int k = 0; k < w; ++k) woff += wsum[k];
    incl += woff;
    if (i < N) rowptr[i] = incl - x;
    if (t == 1023) bsum[blockIdx.x] = incl;
}

__global__ void k_scan2(const int* __restrict__ bsum, int* __restrict__ boff,
                        int* __restrict__ rowptr, int NBLK, int N)
{
    if (threadIdx.x == 0 && blockIdx.x == 0) {
        int run = 0;
        for (int b = 0; b < NBLK; ++b) { boff[b] = run; run += bsum[b]; }
        rowptr[N] = run;
    }
}

__global__ __launch_bounds__(1024) void k_scan3(int* __restrict__ rowptr,
                                                const int* __restrict__ boff, int N)
{
    int i = blockIdx.x * 1024 + threadIdx.x;
    if (i < N) rowptr[i] += boff[blockIdx.x];
}

// CSR build pass 2: pure scattered writes, no atomics.
__global__ void k_scatter(const int* __restrict__ esrc, const int* __restrict__ edst,
                          int E, int Etot, const int* __restrict__ rowptr,
                          const int* __restrict__ pos, int* __restrict__ sidx)
{
    int i = blockIdx.x * blockDim.x + threadIdx.x;
    if (i >= Etot) return;
    int s, d;
    if (i < E) { s = esrc[i]; d = edst[i]; }
    else { s = i - E; d = s; }
    sidx[rowptr[d] + pos[i]] = s;
}

// Per-node: xl = f @ Wl, xr = f @ Wr where f = concat(s0,s1,s2,x1) (NS of s* used).
template <int NS>
__global__ void k_transform(const float* __restrict__ s0, const float* __restrict__ s1,
                            const float* __restrict__ s2, const float* __restrict__ x1,
                            const float* __restrict__ Wl, const float* __restrict__ Wr,
                            float* __restrict__ XL, float* __restrict__ XR, int N)
{
    constexpr int FIN = NS * 10 + 15;
    __shared__ float sWl[FIN * 10];
    __shared__ float sWr[FIN * 10];
    for (int i = threadIdx.x; i < FIN * 10; i += blockDim.x) {
        sWl[i] = Wl[i];
        sWr[i] = Wr[i];
    }
    __syncthreads();
    int n = blockIdx.x * blockDim.x + threadIdx.x;
    if (n >= N) return;
    float f[FIN];
    int o = 0;
    if constexpr (NS >= 1) {
#pragma unroll
        for (int g = 0; g < 10; ++g) f[o++] = s0[n * PAD + g];
    }
    if constexpr (NS >= 2) {
#pragma unroll
        for (int g = 0; g < 10; ++g) f[o++] = s1[n * PAD + g];
    }
    if constexpr (NS >= 3) {
#pragma unroll
        for (int g = 0; g < 10; ++g) f[o++] = s2[n * PAD + g];
    }
#pragma unroll
    for (int k = 0; k < 15; ++k) f[o++] = x1[n * 15 + k];
#pragma unroll
    for (int g = 0; g < 10; ++g) {
        float al = 0.f, ar = 0.f;
#pragma unroll
        for (int k = 0; k < FIN; ++k) {
            al += f[k] * sWl[k * 10 + g];
            ar += f[k] * sWr[k * 10 + g];
        }
        XL[n * PAD + g] = al;
        XR[n * PAD + g] = ar;
    }
    XL[n * PAD + 10] = 0.f; XL[n * PAD + 11] = 0.f;
    XR[n * PAD + 10] = 0.f; XR[n * PAD + 11] = 0.f;
}

// CSR gather + edge softmax + finalize, fused. 8 lanes per dst node.
// e = lrelu(xl[s]+xr[d])@att; ex = exp(e) (no segment_max: |e| <~ 1.5);
// out = relu(sum(ex*xl)/sum(ex) + bias).
__global__ __launch_bounds__(256) void k_gather(
    const int* __restrict__ rowptr, const int* __restrict__ deg,
    const int* __restrict__ sidx,
    const float* __restrict__ XL, const float* __restrict__ XR,
    const float* __restrict__ att, const float* __restrict__ b,
    float* __restrict__ xo, int N)
{
    __shared__ float satt[10], sb[10];
    if (threadIdx.x < 10) { satt[threadIdx.x] = att[threadIdx.x]; sb[threadIdx.x] = b[threadIdx.x]; }
    __syncthreads();
    int node = blockIdx.x * 32 + (threadIdx.x >> 3);
    int l8 = threadIdx.x & 7;
    float acc[10];
#pragma unroll
    for (int g = 0; g < 10; ++g) acc[g] = 0.f;
    float den = 0.f;
    if (node < N) {
        const float4* pr = (const float4*)(XR + node * PAD);
        float4 r0 = pr[0], r1 = pr[1], r2 = pr[2];
        float xr[10] = {r0.x, r0.y, r0.z, r0.w, r1.x, r1.y, r1.z, r1.w, r2.x, r2.y};
        int start = rowptr[node];
        int dgr = deg[node];
        for (int j = l8; j < dgr; j += 8) {
            int s = sidx[start + j];
            const float4* pl = (const float4*)(XL + s * PAD);
            float4 l0 = pl[0], l1 = pl[1], l2 = pl[2];
            float xl[10] = {l0.x, l0.y, l0.z, l0.w, l1.x, l1.y, l1.z, l1.w, l2.x, l2.y};
            float e = 0.f;
#pragma unroll
            for (int g = 0; g < 10; ++g) e += lrelu02(xl[g] + xr[g]) * satt[g];
            float ex = __expf(e);
#pragma unroll
            for (int g = 0; g < 10; ++g) acc[g] += ex * xl[g];
            den += ex;
        }
    }
    // reduce across the 8 lanes of this node's group (xor stays in group)
#pragma unroll
    for (int off = 1; off < 8; off <<= 1) {
        den += __shfl_xor(den, off);
#pragma unroll
        for (int g = 0; g < 10; ++g) acc[g] += __shfl_xor(acc[g], off);
    }
    if (node < N && l8 == 0) {
        float inv = 1.f / den;
#pragma unroll
        for (int g = 0; g < 10; ++g)
            xo[node * PAD + g] = fmaxf(acc[g] * inv + sb[g], 0.f);
        xo[node * PAD + 10] = 0.f;
        xo[node * PAD + 11] = 0.f;
    }
}

// Value head accumulation: per node w = exp(v@va+vab), wv = w*(v@vv+vvb).
__global__ void k_value(const float* __restrict__ xc, const float* __restrict__ x1,
                        const float* __restrict__ x2,
                        const float* __restrict__ vtW, const float* __restrict__ vtb,
                        const float* __restrict__ vaW, const float* __restrict__ vab,
                        const float* __restrict__ vvW, const float* __restrict__ vvb,
                        float* __restrict__ vsums, int N)
{
    __shared__ float sW[580];   // 29x20
    __shared__ float svv[200];  // 20x10
    __shared__ float sb20[20], sva[20], svvb[10], sx2[4];
    __shared__ float svab;
    __shared__ float sred[4][11];
    int t = threadIdx.x;
    for (int i = t; i < 580; i += blockDim.x) sW[i] = vtW[i];
    for (int i = t; i < 200; i += blockDim.x) svv[i] = vvW[i];
    if (t < 20) sb20[t] = vtb[t];
    if (t >= 32 && t < 52) sva[t - 32] = vaW[t - 32];
    if (t >= 64 && t < 74) svvb[t - 64] = vvb[t - 64];
    if (t >= 96 && t < 100) sx2[t - 96] = x2[t - 96];
    if (t == 128) svab = vab[0];
    __syncthreads();
    int n = blockIdx.x * blockDim.x + t;
    float w = 0.f;
    float wv[10];
#pragma unroll
    for (int c = 0; c < 10; ++c) wv[c] = 0.f;
    if (n < N) {
        float f[29];
#pragma unroll
        for (int k = 0; k < 10; ++k) f[k] = xc[n * PAD + k];
#pragma unroll
        for (int k = 0; k < 15; ++k) f[10 + k] = x1[n * 15 + k];
#pragma unroll
        for (int k = 0; k < 4; ++k) f[25 + k] = sx2[k];
        float v[20];
#pragma unroll
        for (int j = 0; j < 20; ++j) {
            float s = sb20[j];
#pragma unroll
            for (int k = 0; k < 29; ++k) s += f[k] * sW[k * 20 + j];
            v[j] = fmaxf(s, 0.f);
        }
        float sc = svab;
#pragma unroll
        for (int j = 0; j < 20; ++j) sc += v[j] * sva[j];
        w = __expf(sc);
#pragma unroll
        for (int c = 0; c < 10; ++c) {
            float t2 = svvb[c];
#pragma unroll
            for (int j = 0; j < 20; ++j) t2 += v[j] * svv[j * 10 + c];
            wv[c] = w * t2;
        }
    }
#pragma unroll
    for (int off = 32; off > 0; off >>= 1) {
        w += __shfl_xor(w, off);
#pragma unroll
        for (int c = 0; c < 10; ++c) wv[c] += __shfl_xor(wv[c], off);
    }
    int wave = t >> 6, lane = t & 63;
    if (lane == 0) {
        sred[wave][0] = w;
#pragma unroll
        for (int c = 0; c < 10; ++c) sred[wave][1 + c] = wv[c];
    }
    __syncthreads();
    if (t == 0) {
#pragma unroll
        for (int c = 0; c < 11; ++c) {
            float s = sred[0][c] + sred[1][c] + sred[2][c] + sred[3][c];
            atomicAdd(&vsums[c], s);
        }
    }
}

// V = tanh(relu(wv/w) @ vl_W + vl_b)
__global__ void k_value2(const float* __restrict__ vsums, const float* __restrict__ vlW,
                         const float* __restrict__ vlb, float* __restrict__ out)
{
    if (threadIdx.x == 0 && blockIdx.x == 0) {
        float inv = 1.f / vsums[0];
        float V = vlb[0];
#pragma unroll
        for (int j = 0; j < 10; ++j) V += fmaxf(vsums[1 + j] * inv, 0.f) * vlW[j];
        out[0] = tanhf(V);
    }
}

// Policy: one wave per move; lane<32 -> attack order, lane in [32,48) -> deploy order.
__global__ __launch_bounds__(256) void k_policy(
    const int* __restrict__ asrc, const int* __restrict__ adst,
    const float* __restrict__ aarm,
    const int* __restrict__ dtgt, const float* __restrict__ darm,
    const float* __restrict__ xc, const float* __restrict__ x1,
    const float* __restrict__ atW, const float* __restrict__ atb,
    const float* __restrict__ dtW, const float* __restrict__ dtb,
    const float* __restrict__ oaW, const float* __restrict__ oab,
    const float* __restrict__ ovW, const float* __restrict__ ovb,
    float* __restrict__ pm, int M)
{
    __shared__ float sat[960];  // 48x20
    __shared__ float sdt[460];  // 23x20
    __shared__ float satb[20], sdtb[20], soa[20], sov[20];
    __shared__ float soab, sovb;
    for (int i = threadIdx.x; i < 960; i += 256) sat[i] = atW[i];
    for (int i = threadIdx.x; i < 460; i += 256) sdt[i] = dtW[i];
    if (threadIdx.x < 20) {
        satb[threadIdx.x] = atb[threadIdx.x];
        sdtb[threadIdx.x] = dtb[threadIdx.x];
        soa[threadIdx.x] = oaW[threadIdx.x];
        sov[threadIdx.x] = ovW[threadIdx.x];
    }
    if (threadIdx.x == 32) { soab = oab[0]; sovb = ovb[0]; }
    __syncthreads();
    int wave = threadIdx.x >> 6, lane = threadIdx.x & 63;
    int m = blockIdx.x * 4 + wave;
    float asc = -1e30f, vsc = 0.f;
    if (m < M) {
        float ord[20];
        bool have = false;
        if (lane < 32) {
            int a = lane;
            int s = asrc[m * 32 + a], d = adst[m * 32 + a];
            float arm = aarm[m * 32 + a];
            float feat[48];
#pragma unroll
            for (int g = 0; g < 10; ++g) feat[g] = xc[s * PAD + g];
#pragma unroll
            for (int g = 0; g < 10; ++g) feat[10 + g] = xc[d * PAD + g];
#pragma unroll
            for (int k = 0; k < 12; ++k) feat[20 + k] = x1[s * 15 + 3 + k];
            float x1d[15];
#pragma unroll
            for (int k = 0; k < 15; ++k) x1d[k] = x1[d * 15 + k];
#pragma unroll
            for (int k = 0; k < 14; ++k) feat[32 + k] = x1d[1 + k];
            feat[46] = arm;
            feat[47] = 0.6f * arm - 0.7f * (x1d[3] + x1d[4]);
#pragma unroll
            for (int j = 0; j < 20; ++j) {
                float s2 = satb[j];
#pragma unroll
                for (int k = 0; k < 48; ++k) s2 += feat[k] * sat[k * 20 + j];
                ord[j] = fmaxf(s2, 0.f);
            }
            have = true;
        } else if (lane < 48) {
            int dd = lane - 32;
            int tg = dtgt[m * 16 + dd];
            float arm = darm[m * 16 + dd];
            float feat[23];
#pragma unroll
            for (int g = 0; g < 10; ++g) feat[g] = xc[tg * PAD + g];
#pragma unroll
            for (int k = 0; k < 12; ++k) feat[10 + k] = x1[tg * 15 + 3 + k];
            feat[22] = arm;
#pragma unroll
            for (int j = 0; j < 20; ++j) {
                float s2 = sdtb[j];
#pragma unroll
                for (int k = 0; k < 23; ++k) s2 += feat[k] * sdt[k * 20 + j];
                ord[j] = fmaxf(s2, 0.f);
            }
            have = true;
        }
        if (have) {
            asc = soab; vsc = sovb;
#pragma unroll
            for (int j = 0; j < 20; ++j) {
                asc += ord[j] * soa[j];
                vsc += ord[j] * sov[j];
            }
        }
    }
    float mx = asc;
#pragma unroll
    for (int off = 32; off > 0; off >>= 1) mx = fmaxf(mx, __shfl_xor(mx, off));
    float p = (asc > -1e29f) ? __expf(asc - mx) : 0.f;
    float num = p * vsc;
    float Z = p;
#pragma unroll
    for (int off = 32; off > 0; off >>= 1) {
        Z += __shfl_xor(Z, off);
        num += __shfl_xor(num, off);
    }
    if (m < M && lane == 0) pm[m] = num / Z;
}

// out[1..M] = log_softmax(pm)
__global__ void k_logsoftmax(const float* __restrict__ pm, float* __restrict__ out, int M)
{
    __shared__ float red[16];
    __shared__ float sval;
    int t = threadIdx.x;
    int wave = t >> 6, lane = t & 63;
    float mx = -1e30f;
    for (int i = t; i < M; i += 1024) mx = fmaxf(mx, pm[i]);
#pragma unroll
    for (int off = 32; off > 0; off >>= 1) mx = fmaxf(mx, __shfl_xor(mx, off));
    if (lane == 0) red[wave] = mx;
    __syncthreads();
    if (t == 0) {
        float m2 = red[0];
        for (int i = 1; i < 16; ++i) m2 = fmaxf(m2, red[i]);
        sval = m2;
    }
    __syncthreads();
    float smax = sval;
    float sum = 0.f;
    for (int i = t; i < M; i += 1024) sum += __expf(pm[i] - smax);
#pragma unroll
    for (int off = 32; off > 0; off >>= 1) sum += __shfl_xor(sum, off);
    if (lane == 0) red[wave] = sum;
    __syncthreads();
    if (t == 0) {
        float s2 = 0.f;
        for (int i = 0; i < 16; ++i) s2 += red[i];
        sval = s2;
    }
    __syncthreads();
    float lse = smax + logf(sval);
    for (int i = t; i < M; i += 1024) out[1 + i] = pm[i] - lse;
}

extern "C" void kernel_launch(void* const* d_in, const int* in_sizes, int n_in,
                              void* d_out, int out_size, void* d_ws, size_t ws_size,
                              hipStream_t stream)
{
    const float* x1   = (const float*)d_in[0];
    const float* x2   = (const float*)d_in[1];
    const int*   edges = (const int*)d_in[2];
    const int*   asrc = (const int*)d_in[3];
    const int*   adst = (const int*)d_in[4];
    const float* aarm = (const float*)d_in[5];
    const int*   dtgt = (const int*)d_in[6];
    const float* darm = (const float*)d_in[7];
    const float* initW = (const float*)d_in[8];
    const float* initb = (const float*)d_in[9];
    const float* g1Wl = (const float*)d_in[10];
    const float* g1Wr = (const float*)d_in[11];
    const float* g1att = (const float*)d_in[12];
    const float* g1b = (const float*)d_in[13];
    const float* g2Wl = (const float*)d_in[14];
    const float* g2Wr = (const float*)d_in[15];
    const float* g2att = (const float*)d_in[16];
    const float* g2b = (const float*)d_in[17];
    const float* g3Wl = (const float*)d_in[18];
    const float* g3Wr = (const float*)d_in[19];
    const float* g3att = (const float*)d_in[20];
    const float* g3b = (const float*)d_in[21];
    const float* vtW = (const float*)d_in[22];
    const float* vtb = (const float*)d_in[23];
    const float* vaW = (const float*)d_in[24];
    const float* vab = (const float*)d_in[25];
    const float* vvW = (const float*)d_in[26];
    const float* vvb = (const float*)d_in[27];
    const float* vlW = (const float*)d_in[28];
    const float* vlb = (const float*)d_in[29];
    const float* atW = (const float*)d_in[30];
    const float* atb = (const float*)d_in[31];
    const float* dtW = (const float*)d_in[32];
    const float* dtb = (const float*)d_in[33];
    const float* oaW = (const float*)d_in[34];
    const float* oab = (const float*)d_in[35];
    const float* ovW = (const float*)d_in[36];
    const float* ovb = (const float*)d_in[37];

    const int N = in_sizes[0] / 15;
    const int E = in_sizes[2] / 2;
    const int M = in_sizes[3] / 32;
    const int Etot = E + N;

    float* ws = (float*)d_ws;
    size_t off = 0;
    float* XU = ws + off; off += (size_t)N * PAD;  // x_
    float* XA = ws + off; off += (size_t)N * PAD;
    float* XB = ws + off; off += (size_t)N * PAD;
    float* XC = ws + off; off += (size_t)N * PAD;
    float* XL = ws + off; off += (size_t)N * PAD;
    float* XR = ws + off; off += (size_t)N * PAD;
    int* sidx = (int*)(ws + off); off += Etot;
    int* deg = (int*)(ws + off); off += N;
    int* rowptr = (int*)(ws + off); off += N + 8;
    int* bsum = (int*)(ws + off); off += 128;
    int* boff = (int*)(ws + off); off += 128;
    float* VS = ws + off; off += 16;
    float* PM = ws + off; off += M;
    // pos overlays XA..XC (3*N*PAD = 3.6M >= Etot); dead before first k_gather.
    int* pos = (int*)XA;

    float* outp = (float*)d_out;

    const int NB = (N + 255) / 256;
    const int EB = (Etot + 255) / 256;
    const int NG = (N + 31) / 32;       // gather: 8 lanes/node, 32 nodes/block
    const int NSC = (N + 1023) / 1024;  // scan blocks
    const int* esrc = edges;
    const int* edst = edges + E;

    k_init<<<NB, 256, 0, stream>>>(x1, initW, initb, XU, deg, VS, N);

    // CSR build (shared by all 3 layers)
    k_hist<<<EB, 256, 0, stream>>>(esrc, edst, E, Etot, deg, pos);
    k_scan1<<<NSC, 1024, 0, stream>>>(deg, rowptr, bsum, N);
    k_scan2<<<1, 64, 0, stream>>>(bsum, boff, rowptr, NSC, N);
    k_scan3<<<NSC, 1024, 0, stream>>>(rowptr, boff, N);
    k_scatter<<<EB, 256, 0, stream>>>(esrc, edst, E, Etot, rowptr, pos, sidx);

    // Layer 1: f = [x_, x1]
    k_transform<1><<<NB, 256, 0, stream>>>(XU, nullptr, nullptr, x1, g1Wl, g1Wr, XL, XR, N);
    k_gather<<<NG, 256, 0, stream>>>(rowptr, deg, sidx, XL, XR, g1att, g1b, XA, N);

    // Layer 2: f = [xa, x_, x1]
    k_transform<2><<<NB, 256, 0, stream>>>(XA, XU, nullptr, x1, g2Wl, g2Wr, XL, XR, N);
    k_gather<<<NG, 256, 0, stream>>>(rowptr, deg, sidx, XL, XR, g2att, g2b, XB, N);

    // Layer 3: f = [xb, xa, x_, x1]
    k_transform<3><<<NB, 256, 0, stream>>>(XB, XA, XU, x1, g3Wl, g3Wr, XL, XR, N);
    k_gather<<<NG, 256, 0, stream>>>(rowptr, deg, sidx, XL, XR, g3att, g3b, XC, N);

    // Value head
    k_value<<<NB, 256, 0, stream>>>(XC, x1, x2, vtW, vtb, vaW, vab, vvW, vvb, VS, N);
    k_value2<<<1, 64, 0, stream>>>(VS, vlW, vlb, outp);

    // Policy head
    k_policy<<<(M + 3) / 4, 256, 0, stream>>>(asrc, adst, aarm, dtgt, darm, XC, x1,
                                              atW, atb, dtW, dtb, oaW, oab, ovW, ovb, PM, M);
    k_logsoftmax<<<1, 1024, 0, stream>>>(PM, outp, M);
}